// Round 11
// baseline (4032.088 us; speedup 1.0000x reference)
//
#include <hip/hip_runtime.h>
#include <hip/hip_bf16.h>
#include <stdint.h>

// Problem constants
#define B_ 4096
#define N_ 32
#define D_ 128
#define E_ 256
#define H_ 8
#define F_ 1024
#define L_ 6
#define M_ (B_ * N_)  // 131072 rows

typedef unsigned short u16;
typedef __attribute__((ext_vector_type(8))) short short8;   // 8 bf16 (MFMA A/B frag)
typedef __attribute__((ext_vector_type(4))) short short4v;  // 4 bf16 (8B)
typedef __attribute__((ext_vector_type(4))) float floatx4;

__device__ __forceinline__ float b2f(u16 u) {
  union { unsigned int i; float f; } c;
  c.i = ((unsigned int)u) << 16;
  return c.f;
}
__device__ __forceinline__ u16 f2b(float f) {
  union { float f; unsigned int i; } c;
  c.f = f;
  unsigned int x = c.i;
  return (u16)((x + 0x7fffu + ((x >> 16) & 1u)) >> 16);  // RNE
}

// async global->LDS DMA, 16B per lane. LDS dest = wave-uniform base + lane*16.
typedef __attribute__((address_space(1))) void* gas_ptr;
typedef __attribute__((address_space(3))) void* las_ptr;
__device__ __forceinline__ void async16(const u16* g, u16* l) {
  __builtin_amdgcn_global_load_lds((gas_ptr)g, (las_ptr)l, 16, 0, 0);
}

#define RAW_BARRIER() __builtin_amdgcn_s_barrier()
#define WAITV(n) asm volatile("s_waitcnt vmcnt(" #n ")" ::: "memory")

// ---------------------------------------------------------------------------
// gemm_async: C[m,n] = A[m,:] @ Bt[n,:] + bias[n], bf16 out (optional ReLU).
// 128x128 tile, 4 waves, mfma_f32_16x16x32_bf16, BK=32, depth-2 DMA pipeline.
// SWAPPED-OPERAND MFMA (round-11): MFMA(weight_frag, act_frag) so each lane
// owns 4 consecutive output cols of one row -> C-stores are 8B short4
// (was 64 scalar 2B stores/thread). K-loop & staging unchanged.
// ---------------------------------------------------------------------------
template <bool RELU>
__global__ __launch_bounds__(256) void gemm_async(
    const u16* __restrict__ A, int lda,
    const u16* __restrict__ Bt,
    const float* __restrict__ bias,
    u16* __restrict__ C, int ldc,
    int K) {
  __shared__ u16 As[3][128 * 32];
  __shared__ u16 Bs[3][128 * 32];
  const int tid = threadIdx.x;
  const int wave = tid >> 6;
  const int lane = tid & 63;
  const int wm = wave & 1;
  const int wn = wave >> 1;
  const int lrow = lane & 15;
  const int quad = lane >> 4;
  const long m0 = (long)blockIdx.x * 128;
  const long n0 = (long)blockIdx.y * 128;

  const u16* Ab = A + m0 * lda;
  const u16* Bb = Bt + n0 * K;

  floatx4 acc[4][4];
#pragma unroll
  for (int a = 0; a < 4; ++a)
#pragma unroll
    for (int b = 0; b < 4; ++b) acc[a][b] = floatx4{0.f, 0.f, 0.f, 0.f};

  const int rr = tid >> 2;       // 0..63
  const int oo = (tid & 3) * 8;  // k sub-offset (elements)

  // 4 DMA requests per thread per tile
#define ISSUE_GA(p, kb)                                              \
  do {                                                               \
    async16(Ab + (long)rr * lda + (kb) + oo, &As[p][wave * 512]);    \
    async16(Ab + (long)(rr + 64) * lda + (kb) + oo,                  \
            &As[p][2048 + wave * 512]);                              \
    async16(Bb + (long)rr * K + (kb) + oo, &Bs[p][wave * 512]);      \
    async16(Bb + (long)(rr + 64) * K + (kb) + oo,                    \
            &Bs[p][2048 + wave * 512]);                              \
  } while (0)

  const int T = K >> 5;
  ISSUE_GA(0, 0);
  if (T > 1) ISSUE_GA(1, 32);
  for (int i = 0; i < T; ++i) {
    const int cur = i % 3;
    RAW_BARRIER();  // all waves done computing tile i-1 -> buffer (i+2)%3 free
    if (i + 2 < T) {
      ISSUE_GA((i + 2) % 3, (i + 2) * 32);
      WAITV(8);  // tile i retired; tiles i+1, i+2 (8 req) still in flight
    } else if (i + 1 < T) {
      WAITV(4);
    } else {
      WAITV(0);
    }
    RAW_BARRIER();  // tile i visible block-wide
    short8 af[4], bfr[4];
#pragma unroll
    for (int t = 0; t < 4; ++t) {
      af[t] = *(const short8*)(&As[cur][(wm * 64 + t * 16 + lrow) * 32 + quad * 8]);
      bfr[t] = *(const short8*)(&Bs[cur][(wn * 64 + t * 16 + lrow) * 32 + quad * 8]);
    }
    // swapped: D[row=quad*4+r -> n][col=lrow -> m]
#pragma unroll
    for (int tm = 0; tm < 4; ++tm)
#pragma unroll
      for (int tn = 0; tn < 4; ++tn)
        acc[tm][tn] = __builtin_amdgcn_mfma_f32_16x16x32_bf16(bfr[tn], af[tm], acc[tm][tn], 0, 0, 0);
  }
#undef ISSUE_GA

  // swapped C/D layout: row = m0+wm*64+tm*16+lrow, col = n0+wn*64+tn*16+quad*4+r
#pragma unroll
  for (int tn = 0; tn < 4; ++tn) {
    const long col0 = n0 + wn * 64 + tn * 16 + quad * 4;
    const floatx4 bv = *(const floatx4*)(bias + col0);
#pragma unroll
    for (int tm = 0; tm < 4; ++tm) {
      const long row = m0 + wm * 64 + tm * 16 + lrow;
      short4v ov;
#pragma unroll
      for (int r = 0; r < 4; ++r) {
        float v = acc[tm][tn][r] + bv[r];
        if (RELU) v = fmaxf(v, 0.0f);
        ov[r] = (short)f2b(v);
      }
      *(short4v*)(&C[row * (long)ldc + col0]) = ov;
    }
  }
}

// ---------------------------------------------------------------------------
// gemm_ln: 64x256 tile, 256 threads (4 waves, one 64-col quarter each),
// depth-1 DMA (verified). SWAPPED-OPERAND MFMA (round-11): lane owns 4
// consecutive cols of one row -> resid/bias/g/b loads and xout stores are
// float4, hout stores are short4 (epilogue ~196 -> ~52 VMEM insts/thread;
// round-10 diagnosis: the scalar epilogue tail was the serialized cost).
// LN reduction moves to quad-axis shfls (16/32) + part[][] (ln_write_h
// pattern, verified in the fused-kernel arc).
// C = A @ Bt^T + bias (+resid); writes xout (fp32) AND hout = LN(C) (bf16).
// ---------------------------------------------------------------------------
template <bool RESID>
__global__ __launch_bounds__(256) void gemm_ln(
    const u16* __restrict__ A, int lda, long sAz,
    const u16* __restrict__ Bt, long sBz,
    const float* __restrict__ bias, long sBiasz,
    float* __restrict__ xout, u16* __restrict__ hout,
    int ldc, long sCz,
    const float* __restrict__ resid,
    const float* __restrict__ g, const float* __restrict__ be,
    int K) {
  __shared__ u16 As[2][64 * 32];     // 4 KB per buf
  __shared__ u16 Bs[2][256 * 32];    // 16 KB per buf
  __shared__ float part[64][4][2];   // per-row partial {sum, sumsq} per wave
  const int tid = threadIdx.x;
  const int wave = tid >> 6;   // 0..3 == wn (col quarter)
  const int lane = tid & 63;
  const int wn = wave;
  const int lrow = lane & 15;
  const int quad = lane >> 4;
  const int z = blockIdx.z;
  const long m0 = (long)blockIdx.x * 64;

  const u16* Ab = A + (long)z * sAz + m0 * lda;
  const u16* Bb = Bt + (long)z * sBz;

  floatx4 acc[4][4];
#pragma unroll
  for (int a = 0; a < 4; ++a)
#pragma unroll
    for (int b = 0; b < 4; ++b) acc[a][b] = floatx4{0.f, 0.f, 0.f, 0.f};

  const int rr = tid >> 2;       // 0..63
  const int oo = (tid & 3) * 8;

  // 5 DMA requests per thread per tile: A 4KB (1) + B 16KB (4)
#define ISSUE_GL(p, kb)                                               \
  do {                                                                \
    async16(Ab + (long)rr * lda + (kb) + oo, &As[p][wave * 512]);     \
    async16(Bb + (long)rr * K + (kb) + oo, &Bs[p][wave * 512]);       \
    async16(Bb + (long)(rr + 64) * K + (kb) + oo,                     \
            &Bs[p][2048 + wave * 512]);                               \
    async16(Bb + (long)(rr + 128) * K + (kb) + oo,                    \
            &Bs[p][4096 + wave * 512]);                               \
    async16(Bb + (long)(rr + 192) * K + (kb) + oo,                    \
            &Bs[p][6144 + wave * 512]);                               \
  } while (0)

  const int T = K >> 5;
  ISSUE_GL(0, 0);
  for (int i = 0; i < T; ++i) {
    const int cur = i & 1;
    RAW_BARRIER();
    if (i + 1 < T) {
      ISSUE_GL(cur ^ 1, (i + 1) * 32);
      WAITV(5);  // tile i's 5 requests retired; tile i+1 in flight
    } else {
      WAITV(0);
    }
    RAW_BARRIER();
    short8 af[4], bfr[4];
#pragma unroll
    for (int t = 0; t < 4; ++t) {
      af[t] = *(const short8*)(&As[cur][(t * 16 + lrow) * 32 + quad * 8]);
      bfr[t] = *(const short8*)(&Bs[cur][(wn * 64 + t * 16 + lrow) * 32 + quad * 8]);
    }
    // swapped: D[row=quad*4+r -> n][col=lrow -> m]
#pragma unroll
    for (int tm = 0; tm < 4; ++tm)
#pragma unroll
      for (int tn = 0; tn < 4; ++tn)
        acc[tm][tn] = __builtin_amdgcn_mfma_f32_16x16x32_bf16(bfr[tn], af[tm], acc[tm][tn], 0, 0, 0);
  }
#undef ISSUE_GL

  // bias (+resid) folded into acc — all float4 (swapped layout:
  // row = m0 + tm*16 + lrow ; col = wn*64 + tn*16 + quad*4 + r)
  const long cz = (long)z * sCz;
#pragma unroll
  for (int tn = 0; tn < 4; ++tn) {
    const int col0 = wn * 64 + tn * 16 + quad * 4;
    const floatx4 bv = *(const floatx4*)(bias + (long)z * sBiasz + col0);
#pragma unroll
    for (int tm = 0; tm < 4; ++tm) {
      const long row = m0 + tm * 16 + lrow;
      floatx4 v = acc[tm][tn] + bv;
      if (RESID) v = v + *(const floatx4*)(resid + cz + row * (long)ldc + col0);
      acc[tm][tn] = v;
    }
  }

  // per-row stats: lane sums its 16 cols, reduce across quads (shfl 16/32),
  // combine the 4 waves via part[][]
#pragma unroll
  for (int tm = 0; tm < 4; ++tm) {
    float s = 0.f, q = 0.f;
#pragma unroll
    for (int tn = 0; tn < 4; ++tn)
#pragma unroll
      for (int r = 0; r < 4; ++r) {
        const float v = acc[tm][tn][r];
        s += v; q += v * v;
      }
    s += __shfl_xor(s, 16, 64); s += __shfl_xor(s, 32, 64);
    q += __shfl_xor(q, 16, 64); q += __shfl_xor(q, 32, 64);
    if (quad == 0) {
      part[tm * 16 + lrow][wn][0] = s;
      part[tm * 16 + lrow][wn][1] = q;
    }
  }
  __syncthreads();

  // LN params per col (float4, shared across tm)
  floatx4 gv4[4], bev4[4];
#pragma unroll
  for (int tn = 0; tn < 4; ++tn) {
    const int col0 = wn * 64 + tn * 16 + quad * 4;
    gv4[tn] = *(const floatx4*)(g + col0);
    bev4[tn] = *(const floatx4*)(be + col0);
  }
#pragma unroll
  for (int tm = 0; tm < 4; ++tm) {
    const int lr = tm * 16 + lrow;
    const float S = part[lr][0][0] + part[lr][1][0] + part[lr][2][0] + part[lr][3][0];
    const float Q = part[lr][0][1] + part[lr][1][1] + part[lr][2][1] + part[lr][3][1];
    const float mean = S * (1.0f / 256.0f);
    const float var = Q * (1.0f / 256.0f) - mean * mean;
    const float rstd = rsqrtf(var + 1e-5f);
    const long row = m0 + lr;
#pragma unroll
    for (int tn = 0; tn < 4; ++tn) {
      const int col0 = wn * 64 + tn * 16 + quad * 4;
      const long idx = cz + row * (long)ldc + col0;
      const floatx4 v = acc[tm][tn];
      *(floatx4*)(&xout[idx]) = v;          // 16B store
      short4v hv;
#pragma unroll
      for (int r = 0; r < 4; ++r)
        hv[r] = (short)f2b((v[r] - mean) * rstd * gv4[tn][r] + bev4[tn][r]);
      *(short4v*)(&hout[idx]) = hv;         // 8B store
    }
  }
}

// ---------------------------------------------------------------------------
// Banded attention (verified round 2). One block per batch; batch's 48KB qkv
// chunk staged to LDS via coalesced global_load_lds with pre-swizzled source.
// ---------------------------------------------------------------------------
__global__ __launch_bounds__(256) void attn_kernel(const u16* __restrict__ qkv,
                                                   u16* __restrict__ o) {
  __shared__ u16 sh[32 * 768];  // 48KB
  const int tid = threadIdx.x;
  const int wave = tid >> 6;
  const int lane = tid & 63;
  const long b = blockIdx.x;
  const u16* src = qkv + b * (32L * 768);

#pragma unroll
  for (int p = 0; p < 12; ++p) {
    const int s = p * 256 + wave * 64 + lane;
    const int row = s / 96;
    const int cir = s - row * 96;
    const int gsl = row * 96 + (cir ^ (row & 7));
    async16(src + (long)gsl * 8, &sh[p * 2048 + wave * 512]);
  }
  WAITV(0);
  __syncthreads();

  const int i = tid & 31;
  const int h = (tid >> 5) & 7;
  const long m = b * 32 + i;

  float q[32];
#pragma unroll
  for (int c = 0; c < 4; ++c) {
    short8 qv = *(const short8*)(&sh[i * 768 + (((h * 4 + c) ^ (i & 7)) << 3)]);
#pragma unroll
    for (int k = 0; k < 8; ++k) q[c * 8 + k] = b2f((u16)qv[k]);
  }
  float sc[3];
  int jc[3];
#pragma unroll
  for (int jj = 0; jj < 3; ++jj) {
    const int j = i - 1 + jj;
    const bool valid = (j >= 0) && (j < 32);
    const int jcl = valid ? j : i;
    jc[jj] = jcl;
    float dot = 0.0f;
#pragma unroll
    for (int c = 0; c < 4; ++c) {
      short8 kv = *(const short8*)(
          &sh[jcl * 768 + ((32 + ((h * 4 + c) ^ (jcl & 7))) << 3)]);
#pragma unroll
      for (int k = 0; k < 8; ++k) dot += q[c * 8 + k] * b2f((u16)kv[k]);
    }
    sc[jj] = valid ? dot * 0.17677669529663687f : -3.0e38f;
  }
  const float mx = fmaxf(sc[0], fmaxf(sc[1], sc[2]));
  const float w0 = __expf(sc[0] - mx);
  const float w1 = __expf(sc[1] - mx);
  const float w2 = __expf(sc[2] - mx);
  const float inv = 1.0f / (w0 + w1 + w2);
  const float w[3] = {w0 * inv, w1 * inv, w2 * inv};
  float acc[32];
#pragma unroll
  for (int k = 0; k < 32; ++k) acc[k] = 0.0f;
#pragma unroll
  for (int jj = 0; jj < 3; ++jj) {
    const int jcl = jc[jj];
    const float wj = w[jj];
#pragma unroll
    for (int c = 0; c < 4; ++c) {
      short8 vv = *(const short8*)(
          &sh[jcl * 768 + ((64 + ((h * 4 + c) ^ (jcl & 7))) << 3)]);
#pragma unroll
      for (int k = 0; k < 8; ++k) acc[c * 8 + k] += wj * b2f((u16)vv[k]);
    }
  }
  u16* op = o + m * 256 + h * 32;
#pragma unroll
  for (int c = 0; c < 4; ++c) {
    short8 ov;
#pragma unroll
    for (int k = 0; k < 8; ++k) ov[k] = (short)f2b(acc[c * 8 + k]);
    *(short8*)(op + c * 8) = ov;
  }
}

// ---------------------------------------------------------------------------
// Prep kernels: fp32 inputs -> bf16 (optionally transposed) weights
// ---------------------------------------------------------------------------
__global__ __launch_bounds__(256) void transpose_f2b(const float* __restrict__ src,
                                                     u16* __restrict__ dst,
                                                     int R, int C) {
  const long base = (long)blockIdx.z * R * C;
  const int idx = blockIdx.x * 256 + threadIdx.x;
  if (idx < R * C) {
    const int r = idx / C;
    const int c = idx - r * C;
    dst[base + (long)c * R + r] = f2b(src[base + idx]);
  }
}

__global__ __launch_bounds__(256) void cvt_f2b_kernel(const float* __restrict__ s,
                                                      u16* __restrict__ d, int n) {
  const int i = blockIdx.x * 256 + threadIdx.x;
  if (i < n) d[i] = f2b(s[i]);
}

__global__ __launch_bounds__(256) void addf_kernel(const float* __restrict__ a,
                                                   const float* __restrict__ b,
                                                   float* __restrict__ d, int n) {
  const int i = blockIdx.x * 256 + threadIdx.x;
  if (i < n) d[i] = a[i] + b[i];
}

// ---------------------------------------------------------------------------
extern "C" void kernel_launch(void* const* d_in, const int* in_sizes, int n_in,
                              void* d_out, int out_size, void* d_ws, size_t ws_size,
                              hipStream_t stream) {
  (void)in_sizes; (void)n_in; (void)out_size; (void)ws_size;
  const float* obs   = (const float*)d_in[0];   // [B,D]
  const float* emb_W = (const float*)d_in[1];   // [N,D,E]
  const float* emb_b = (const float*)d_in[2];   // [N,E]
  const float* pos   = (const float*)d_in[3];   // [N,E]
  const float* Wqkv  = (const float*)d_in[4];   // [3E,E] ([N,K] layout)
  const float* bqkv  = (const float*)d_in[5];   // [3E]
  const float* Wo    = (const float*)d_in[6];   // [E,E]  ([N,K])
  const float* bo    = (const float*)d_in[7];   // [E]
  const float* ln1_g = (const float*)d_in[8];
  const float* ln1_b = (const float*)d_in[9];
  const float* ln2_g = (const float*)d_in[10];
  const float* ln2_b = (const float*)d_in[11];
  const float* W1    = (const float*)d_in[12];  // [E,F] -> [F,E]
  const float* b1    = (const float*)d_in[13];  // [F]
  const float* W2    = (const float*)d_in[14];  // [F,E] -> [E,F]
  const float* b2    = (const float*)d_in[15];  // [E]
  // d_in[16] = adj_mask: band |i-j|<=1 hardcoded (exact, see attn_kernel)

  float* x = (float*)d_out;  // fp32 residual stream lives in d_out

  char* ws = (char*)d_ws;
  u16* hbuf   = (u16*)ws;   ws += (size_t)M_ * E_ * 2;        // LN out / attn out
  u16* sbuf   = (u16*)ws;   ws += (size_t)M_ * F_ * 2;        // qkv / ffn act
  u16* embWt  = (u16*)ws;   ws += (size_t)N_ * D_ * E_ * 2;   // [N,E,D] bf16
  u16* obs_bf = (u16*)ws;   ws += (size_t)B_ * D_ * 2;
  u16* wqkv_bf= (u16*)ws;   ws += (size_t)3 * E_ * E_ * 2;
  u16* wo_bf  = (u16*)ws;   ws += (size_t)E_ * E_ * 2;
  u16* w1t    = (u16*)ws;   ws += (size_t)E_ * F_ * 2;        // [F,E] bf16
  u16* w2t    = (u16*)ws;   ws += (size_t)E_ * F_ * 2;        // [E,F] bf16
  float* cbias= (float*)ws; ws += (size_t)N_ * E_ * 4;        // emb_b + pos

  // --- prep (once per launch) ---
  transpose_f2b<<<dim3((D_ * E_ + 255) / 256, 1, N_), 256, 0, stream>>>(emb_W, embWt, D_, E_);
  transpose_f2b<<<dim3((E_ * F_ + 255) / 256, 1, 1), 256, 0, stream>>>(W1, w1t, E_, F_);
  transpose_f2b<<<dim3((E_ * F_ + 255) / 256, 1, 1), 256, 0, stream>>>(W2, w2t, F_, E_);
  cvt_f2b_kernel<<<(B_ * D_ + 255) / 256, 256, 0, stream>>>(obs, obs_bf, B_ * D_);
  cvt_f2b_kernel<<<(3 * E_ * E_ + 255) / 256, 256, 0, stream>>>(Wqkv, wqkv_bf, 3 * E_ * E_);
  cvt_f2b_kernel<<<(E_ * E_ + 255) / 256, 256, 0, stream>>>(Wo, wo_bf, E_ * E_);
  addf_kernel<<<(N_ * E_ + 255) / 256, 256, 0, stream>>>(emb_b, pos, cbias, N_ * E_);

  // --- tokenizer + fused LN1: x[b,n,:] = obs[b,:] @ emb_W[n] + cbias[n,:] ---
  gemm_ln<false><<<dim3(B_ / 64, 1, N_), 256, 0, stream>>>(
      obs_bf, D_, 0, embWt, (long)E_ * D_, cbias, E_,
      x, hbuf, N_ * E_, E_, nullptr, ln1_g, ln1_b, D_);

  // --- L encoder layers (shared weights) ---
  for (int l = 0; l < L_; ++l) {
    // qkv = LN1(x) @ Wqkv^T + bqkv
    gemm_async<false><<<dim3(M_ / 128, 768 / 128, 1), 256, 0, stream>>>(
        hbuf, E_, wqkv_bf, bqkv, sbuf, 768, E_);
    attn_kernel<<<B_, 256, 0, stream>>>(sbuf, hbuf);
    // x += o @ Wo^T + bo;  hbuf = LN2(x)
    gemm_ln<true><<<dim3(M_ / 64, 1, 1), 256, 0, stream>>>(
        hbuf, E_, 0, wo_bf, 0, bo, 0,
        x, hbuf, E_, 0, x, ln2_g, ln2_b, E_);
    // act = relu(LN2 @ W1 + b1)
    gemm_async<true><<<dim3(M_ / 128, F_ / 128, 1), 256, 0, stream>>>(
        hbuf, E_, w1t, b1, sbuf, F_, E_);
    // x += act @ W2^T + b2;  hbuf = LN1(x) for next layer
    gemm_ln<true><<<dim3(M_ / 64, 1, 1), 256, 0, stream>>>(
        sbuf, F_, 0, w2t, 0, b2, 0,
        x, hbuf, E_, 0, x, ln1_g, ln1_b, F_);
  }
  // x == d_out: done (last gemm_ln's hbuf write is benign dead work).
}